// Round 1
// baseline (1011.815 us; speedup 1.0000x reference)
//
#include <hip/hip_runtime.h>
#include <math.h>

#define S 512
#define DIN 256
#define H 512

// ---------------------------------------------------------------------------
// Kernel 1: stable rank sort of 512 timestamps (matches jnp.argsort stable).
// One block, 512 threads. O(S^2) compares via LDS.
// ---------------------------------------------------------------------------
__global__ __launch_bounds__(512) void sort_kernel(
    const float* __restrict__ ts, const float* __restrict__ amp,
    int* __restrict__ order, float* __restrict__ ts_s, float* __restrict__ amp_s)
{
    __shared__ float sts[S];
    int i = threadIdx.x;
    sts[i] = ts[i];
    __syncthreads();
    float ti = sts[i];
    int rank = 0;
    for (int j = 0; j < S; ++j) {
        float tj = sts[j];
        rank += (tj < ti) || (tj == ti && j < i);
    }
    order[rank] = i;
    ts_s[rank]  = ti;
    amp_s[rank] = amp[i];
}

// Block-wide mean/rsqrt(var+eps) over 512 values held as 2 per thread (256 thr).
__device__ __forceinline__ void block_stats_512(float s, float ss, float* red,
                                                float& mean, float& inv)
{
    // wave64 butterfly-free down-reduce
    for (int off = 32; off > 0; off >>= 1) {
        s  += __shfl_down(s, off);
        ss += __shfl_down(ss, off);
    }
    int wid = threadIdx.x >> 6;
    if ((threadIdx.x & 63) == 0) { red[wid] = s; red[4 + wid] = ss; }
    __syncthreads();
    if (threadIdx.x == 0) {
        float Sm  = red[0] + red[1] + red[2] + red[3];
        float SSm = red[4] + red[5] + red[6] + red[7];
        float m = Sm * (1.0f / 512.0f);
        float v = SSm * (1.0f / 512.0f) - m * m;
        red[8] = m;
        red[9] = rsqrtf(v + 1e-5f);
    }
    __syncthreads();
    mean = red[8];
    inv  = red[9];
}

// ---------------------------------------------------------------------------
// Kernel 2: fused per-row encoder. One block (256 thr) per sorted event row.
//   h   = LN(relu(f@We1+be1)@We2+be2)
//   t   = relu(ts*Wt1+bt1)@Wt2+bt2
//   cmb = LN(([h | t | t] * amp) @ Wc + bc)
//   ctx = cmb + sinusoidal_pe(r)
// ---------------------------------------------------------------------------
__global__ __launch_bounds__(256) void encoder_kernel(
    const int* __restrict__ order, const float* __restrict__ ts_s,
    const float* __restrict__ amp_s, const float* __restrict__ feats,
    const float* __restrict__ We1, const float* __restrict__ be1,
    const float* __restrict__ We2, const float* __restrict__ be2,
    const float* __restrict__ g_ev, const float* __restrict__ b_ev,
    const float* __restrict__ Wt1, const float* __restrict__ bt1,
    const float* __restrict__ Wt2, const float* __restrict__ bt2,
    const float* __restrict__ Wc, const float* __restrict__ bc,
    const float* __restrict__ g_sr, const float* __restrict__ b_sr,
    float* __restrict__ ctx)
{
    __shared__ float sf[DIN];
    __shared__ float sh1[256];
    __shared__ float sth[128];
    __shared__ float scomb[1024];
    __shared__ float red[16];

    int r = blockIdx.x;
    int t = threadIdx.x;
    int o = order[r];
    sf[t] = feats[o * DIN + t];
    float x = ts_s[r];
    if (t < 128) sth[t] = fmaxf(fmaf(x, Wt1[t], bt1[t]), 0.0f);
    __syncthreads();

    // hidden1 = relu(sf @ We1 + be1)   [256]
    float acc = be1[t];
    #pragma unroll 4
    for (int d = 0; d < DIN; ++d) acc = fmaf(sf[d], We1[d * 256 + t], acc);
    sh1[t] = fmaxf(acc, 0.0f);
    __syncthreads();

    // h = sh1 @ We2 + be2   [512], 2 cols/thread
    float a0 = be2[t], a1 = be2[t + 256];
    #pragma unroll 4
    for (int k = 0; k < 256; ++k) {
        float hv = sh1[k];
        a0 = fmaf(hv, We2[k * 512 + t], a0);
        a1 = fmaf(hv, We2[k * 512 + t + 256], a1);
    }
    float m, inv;
    block_stats_512(a0 + a1, a0 * a0 + a1 * a1, red, m, inv);
    float ampv = amp_s[r];
    scomb[t]       = fmaf((a0 - m) * inv, g_ev[t],       b_ev[t])       * ampv;
    scomb[t + 256] = fmaf((a1 - m) * inv, g_ev[t + 256], b_ev[t + 256]) * ampv;

    // temporal layer 2: t[c] = sth @ Wt2 + bt2   [256], tiled x2
    float tv = bt2[t];
    #pragma unroll 4
    for (int k = 0; k < 128; ++k) tv = fmaf(sth[k], Wt2[k * 256 + t], tv);
    tv *= ampv;
    scomb[512 + t] = tv;
    scomb[768 + t] = tv;
    __syncthreads();

    // comb @ Wc + bc   [512], 2 cols/thread
    float c0 = bc[t], c1 = bc[t + 256];
    #pragma unroll 4
    for (int u = 0; u < 1024; ++u) {
        float uv = scomb[u];
        c0 = fmaf(uv, Wc[u * 512 + t], c0);
        c1 = fmaf(uv, Wc[u * 512 + t + 256], c1);
    }
    float m2, inv2;
    block_stats_512(c0 + c1, c0 * c0 + c1 * c1, red, m2, inv2);
    float e0 = fmaf((c0 - m2) * inv2, g_sr[t],       b_sr[t]);
    float e1 = fmaf((c1 - m2) * inv2, g_sr[t + 256], b_sr[t + 256]);

    // sinusoidal positional encoding: te[r, 2k]=sin(r*div[k]), te[r,2k+1]=cos
    const float NEG_LN1E4_OVER_H = -9.210340371976184f / 512.0f;
    float rf = (float)r;
    {
        int k0 = t >> 1;
        float ang0 = rf * expf((float)(2 * k0) * NEG_LN1E4_OVER_H);
        e0 += (t & 1) ? cosf(ang0) : sinf(ang0);
        int c = t + 256;
        int k1 = c >> 1;
        float ang1 = rf * expf((float)(2 * k1) * NEG_LN1E4_OVER_H);
        e1 += (c & 1) ? cosf(ang1) : sinf(ang1);
    }
    ctx[r * 512 + t]       = e0;
    ctx[r * 512 + t + 256] = e1;
}

// ---------------------------------------------------------------------------
// Kernel 3: Q/K/V projections, 4 rows per block (weight dword reused 4x).
// Q,V -> d_out; Kbase -> workspace.
// ---------------------------------------------------------------------------
__global__ __launch_bounds__(256) void qkv_kernel(
    const float* __restrict__ ctx,
    const float* __restrict__ Wq, const float* __restrict__ bq,
    const float* __restrict__ Wk, const float* __restrict__ bk,
    const float* __restrict__ Wv, const float* __restrict__ bv,
    float* __restrict__ Qout, float* __restrict__ Kbase, float* __restrict__ Vout)
{
    __shared__ float sc[4][512];
    int r0 = blockIdx.x * 4;
    int t = threadIdx.x;
    #pragma unroll
    for (int rr = 0; rr < 4; ++rr) {
        sc[rr][t]       = ctx[(r0 + rr) * 512 + t];
        sc[rr][t + 256] = ctx[(r0 + rr) * 512 + t + 256];
    }
    __syncthreads();

    float q0[4], q1[4], k0[4], k1[4], v0[4], v1[4];
    float bq0 = bq[t], bq1 = bq[t + 256];
    float bk0 = bk[t], bk1 = bk[t + 256];
    float bv0 = bv[t], bv1 = bv[t + 256];
    #pragma unroll
    for (int rr = 0; rr < 4; ++rr) {
        q0[rr] = bq0; q1[rr] = bq1;
        k0[rr] = bk0; k1[rr] = bk1;
        v0[rr] = bv0; v1[rr] = bv1;
    }
    #pragma unroll 2
    for (int h = 0; h < 512; ++h) {
        float wq0 = Wq[h * 512 + t], wq1 = Wq[h * 512 + t + 256];
        float wk0 = Wk[h * 512 + t], wk1 = Wk[h * 512 + t + 256];
        float wv0 = Wv[h * 512 + t], wv1 = Wv[h * 512 + t + 256];
        #pragma unroll
        for (int rr = 0; rr < 4; ++rr) {
            float cv = sc[rr][h];
            q0[rr] = fmaf(cv, wq0, q0[rr]);
            q1[rr] = fmaf(cv, wq1, q1[rr]);
            k0[rr] = fmaf(cv, wk0, k0[rr]);
            k1[rr] = fmaf(cv, wk1, k1[rr]);
            v0[rr] = fmaf(cv, wv0, v0[rr]);
            v1[rr] = fmaf(cv, wv1, v1[rr]);
        }
    }
    #pragma unroll
    for (int rr = 0; rr < 4; ++rr) {
        int r = r0 + rr;
        Qout[r * 512 + t]        = q0[rr];
        Qout[r * 512 + t + 256]  = q1[rr];
        Kbase[r * 512 + t]       = k0[rr];
        Kbase[r * 512 + t + 256] = k1[rr];
        Vout[r * 512 + t]        = v0[rr];
        Vout[r * 512 + t + 256]  = v1[rr];
    }
}

// ---------------------------------------------------------------------------
// Kernel 4: K[i,j,h] = Kbase[j,h] + 0.1/(1+|i-j|).  537 MB write-bound.
// Block = (i-chunk, j); Kbase row held in registers across 128 i values.
// Fully coalesced float4 stores (1 KiB per wave-store).
// ---------------------------------------------------------------------------
__global__ __launch_bounds__(128) void kexpand_kernel(
    const float* __restrict__ Kbase, float* __restrict__ Kout)
{
    int j  = blockIdx.y;            // 0..511
    int i0 = blockIdx.x * 128;      // i-chunk
    int t  = threadIdx.x;           // 0..127 -> float4 lane
    float4 kb = ((const float4*)(Kbase + j * 512))[t];
    float4* out = (float4*)Kout;
    size_t base = (size_t)j * 128 + t;
    #pragma unroll 4
    for (int ii = 0; ii < 128; ++ii) {
        int i = i0 + ii;
        int d = i - j; if (d < 0) d = -d;
        float conn = 0.1f / (float)(1 + d);
        float4 v;
        v.x = kb.x + conn; v.y = kb.y + conn;
        v.z = kb.z + conn; v.w = kb.w + conn;
        out[base + (size_t)i * 65536] = v;   // 65536 float4 per i-slab
    }
}

extern "C" void kernel_launch(void* const* d_in, const int* in_sizes, int n_in,
                              void* d_out, int out_size, void* d_ws, size_t ws_size,
                              hipStream_t stream) {
    const float* timestamps = (const float*)d_in[0];
    const float* features   = (const float*)d_in[1];
    const float* amplitudes = (const float*)d_in[2];
    // d_in[3] = neuron_ids (unused by reference)
    const float* We1 = (const float*)d_in[4];
    const float* be1 = (const float*)d_in[5];
    const float* We2 = (const float*)d_in[6];
    const float* be2 = (const float*)d_in[7];
    const float* g_ev = (const float*)d_in[8];
    const float* b_ev = (const float*)d_in[9];
    const float* Wt1 = (const float*)d_in[10];
    const float* bt1 = (const float*)d_in[11];
    const float* Wt2 = (const float*)d_in[12];
    const float* bt2 = (const float*)d_in[13];
    const float* Wc  = (const float*)d_in[14];
    const float* bc  = (const float*)d_in[15];
    const float* g_sr = (const float*)d_in[16];
    const float* b_sr = (const float*)d_in[17];
    const float* Wq = (const float*)d_in[18];
    const float* bq = (const float*)d_in[19];
    const float* Wk = (const float*)d_in[20];
    const float* bk = (const float*)d_in[21];
    const float* Wv = (const float*)d_in[22];
    const float* bv = (const float*)d_in[23];

    // Output layout: Q [1,512,512] | K [512,512,512] | V [1,512,512]
    float* Qout = (float*)d_out;
    float* Kout = (float*)d_out + 262144;
    float* Vout = (float*)d_out + 262144 + 512 * 512 * 512;

    // Workspace layout (~2.1 MB)
    char* ws = (char*)d_ws;
    int*   order = (int*)ws;    ws += 512 * sizeof(int);
    float* ts_s  = (float*)ws;  ws += 512 * sizeof(float);
    float* amp_s = (float*)ws;  ws += 512 * sizeof(float);
    float* ctx   = (float*)ws;  ws += 262144 * sizeof(float);
    float* Kbase = (float*)ws;

    sort_kernel<<<1, 512, 0, stream>>>(timestamps, amplitudes, order, ts_s, amp_s);
    encoder_kernel<<<512, 256, 0, stream>>>(order, ts_s, amp_s, features,
        We1, be1, We2, be2, g_ev, b_ev, Wt1, bt1, Wt2, bt2, Wc, bc, g_sr, b_sr, ctx);
    qkv_kernel<<<128, 256, 0, stream>>>(ctx, Wq, bq, Wk, bk, Wv, bv, Qout, Kbase, Vout);
    kexpand_kernel<<<dim3(4, 512), 128, 0, stream>>>(Kbase, Kout);
}